// Round 4
// baseline (1302.531 us; speedup 1.0000x reference)
//
#include <hip/hip_runtime.h>

// ---------------- problem constants ----------------
constexpr int S    = 8192;
constexpr int D    = 768;
constexpr int NMID = 10;
constexpr int EPH  = 820;   // ceil(8192/10)
constexpr int NB   = 768;   // persistent grid (3 blocks/CU on 256 CUs)

// ---------------- workspace layout (float element offsets) ----------------
constexpr int PART_ADJ = 0;       // 600 adjacency partials [pair*6+split]
constexpr int PART_MID = 1024;    // 5*10*768 = 38400 mid partials [sp][cl][col]
constexpr int OFF_MATT = 39424;   // 7680 (atomic)
constexpr int OFF_Y1   = 47104;   // 7680 (atomic)
constexpr int OFF_Z2   = 54784;   // 3840 (atomic)
constexpr int OFF_Y2   = 58624;   // 3840 (atomic)
constexpr int ZERO_N   = 23040;   // MATT..Y2 zero range (starts at OFF_MATT)
constexpr int OFF_MID  = 62464;   // 7680
constexpr int OFF_XMID = 70144;   // 7680
constexpr int OFF_SC   = 77824;   // 81920 raw masked scores [8192][10]
constexpr int OFF_SCB  = 159744;  // 256*20 per-block softmax stats
constexpr int OFF_PVP  = 164864;  // 64*10*768 PV partials
constexpr int OFF_BAR  = 656384;  // uint cnt @+0, uint gen @+16

// ---------------- device-wide barrier (generation-based) ----------------
__device__ __forceinline__ void gbar(unsigned* bar) {
    __syncthreads();
    if (threadIdx.x == 0) {
        __threadfence();   // release all prior global writes (agent scope)
        unsigned g = __hip_atomic_load(bar + 16, __ATOMIC_RELAXED, __HIP_MEMORY_SCOPE_AGENT);
        unsigned a = __hip_atomic_fetch_add(bar, 1u, __ATOMIC_ACQ_REL, __HIP_MEMORY_SCOPE_AGENT);
        if (a == (unsigned)(NB - 1)) {
            __hip_atomic_store(bar, 0u, __ATOMIC_RELAXED, __HIP_MEMORY_SCOPE_AGENT);
            __hip_atomic_fetch_add(bar + 16, 1u, __ATOMIC_RELEASE, __HIP_MEMORY_SCOPE_AGENT);
        } else {
            while (__hip_atomic_load(bar + 16, __ATOMIC_ACQUIRE, __HIP_MEMORY_SCOPE_AGENT) == g)
                __builtin_amdgcn_s_sleep(16);
        }
        __threadfence();   // acquire
    }
    __syncthreads();
}

// out[NR][768] += mi[NR][16] @ W[kb:kb+16][768]  (atomic, 48-way k-split)
template <int NR>
__device__ __forceinline__ void mm_core(const float* __restrict__ W,
                                        const float* mi,
                                        float* __restrict__ out, int kb) {
    int c = threadIdx.x;
    float a0[NR], a1[NR], a2[NR];
#pragma unroll
    for (int i = 0; i < NR; ++i) { a0[i] = 0.f; a1[i] = 0.f; a2[i] = 0.f; }
    for (int kk = 0; kk < 16; ++kk) {
        const float* wr = W + (size_t)(kb + kk) * D;
        float w0 = wr[c], w1 = wr[c + 256], w2 = wr[c + 512];
#pragma unroll
        for (int i = 0; i < NR; ++i) {
            float m = mi[i * 16 + kk];
            a0[i] += m * w0; a1[i] += m * w1; a2[i] += m * w2;
        }
    }
#pragma unroll
    for (int i = 0; i < NR; ++i) {
        atomicAdd(&out[i * D + c],       a0[i]);
        atomicAdd(&out[i * D + c + 256], a1[i]);
        atomicAdd(&out[i * D + c + 512], a2[i]);
    }
}

// ---------------- init: zero barrier words ----------------
__global__ void k_init(float* ws) {
    if (threadIdx.x < 32) ((unsigned*)(ws + OFF_BAR))[threadIdx.x] = 0u;
}

// ---------------- the persistent kernel ----------------
__global__ __launch_bounds__(256, 3) void k_main(const float* __restrict__ A,
                                                 const float* __restrict__ x,
                                                 const float* __restrict__ attL,
                                                 const float* __restrict__ W1,
                                                 const float* __restrict__ b1,
                                                 const float* __restrict__ attH,
                                                 const float* __restrict__ W2,
                                                 const float* __restrict__ b2,
                                                 float* __restrict__ ws,
                                                 float* __restrict__ out) {
    __shared__ float lds[8000];   // 32 KB, aliased across phases
    unsigned* bar = (unsigned*)(ws + OFF_BAR);
    int bx = blockIdx.x, tid = threadIdx.x;

    // ---------------- P0: adjacency partials + mid partials + zeroing ----------------
    if (bx < 600) {
        int p = bx / 6, s = bx % 6;
        int i = p / 10, j = p % 10;
        int r0 = i * EPH, nr = min(EPH, S - r0);
        int c0 = j * EPH, nc = min(EPH, S - c0);
        int rs0 = r0 + (nr * s) / 6, rs1 = r0 + (nr * (s + 1)) / 6;
        int nc4 = nc >> 2;
        float acc = 0.f;
        if (tid < nc4) {
            const float* base = A + (size_t)rs0 * S + c0 + tid * 4;
            int n = rs1 - rs0;
#pragma unroll 4
            for (int r = 0; r < n; ++r) {
                float4 v = *(const float4*)(base + (size_t)r * S);
                acc += (v.x + v.y) + (v.z + v.w);
            }
        }
#pragma unroll
        for (int off = 32; off > 0; off >>= 1) acc += __shfl_down(acc, off, 64);
        if ((tid & 63) == 0) lds[tid >> 6] = acc;
        __syncthreads();
        if (tid == 0) ws[PART_ADJ + bx] = (lds[0] + lds[1]) + (lds[2] + lds[3]);
    } else if (bx < 750) {
        int item = bx - 600;                 // 150 items: 10 cl x 3 cc x 5 sp
        int cl = item / 15, rem = item % 15;
        int cc = rem / 5, sp = rem % 5;
        int r0 = cl * EPH, nr = min(EPH, S - r0);
        int rs0 = r0 + (nr * sp) / 5, rs1 = r0 + (nr * (sp + 1)) / 5;
        int c = cc * 256 + tid;
        float acc = 0.f;
#pragma unroll 4
        for (int r = rs0; r < rs1; ++r) acc += x[(size_t)r * D + c];
        ws[PART_MID + (sp * NMID + cl) * D + c] = acc;
    } else {
        for (int t = (bx - 750) * 256 + tid; t < ZERO_N; t += 18 * 256)
            ws[OFF_MATT + t] = 0.f;
    }
    gbar(bar);

    // ---------------- P1: reduce mid + mid @ attL -> MATT ----------------
    if (bx < 48) {
        int kb = bx * 16;
        if (tid < 160) {
            int cl = tid >> 4, k = tid & 15;
            float s = 0.f;
#pragma unroll
            for (int sp = 0; sp < 5; ++sp)
                s += ws[PART_MID + (sp * NMID + cl) * D + kb + k];
            lds[tid] = s;
            ws[OFF_MID + cl * D + kb + k] = s;
        }
        __syncthreads();
        mm_core<10>(attL, lds, ws + OFF_MATT, kb);
    }
    gbar(bar);

    // ---------------- P2: scores + per-block softmax stats ----------------
    if (bx < 256) {
        float* ma  = lds;          // 7680
        float* scl = lds + 7680;   // 320
        for (int t = tid; t < NMID * D; t += 256) ma[t] = ws[OFF_MATT + t];
        __syncthreads();
        const float4* maf = (const float4*)ma;
        const float4* x4  = (const float4*)x;
        int wave = tid >> 6, ln = tid & 63;
        int rbase = bx * 32 + wave * 8;
        for (int rr = 0; rr < 8; ++rr) {
            int r = rbase + rr;
            float4 v0 = x4[(size_t)r * 192 + ln];
            float4 v1 = x4[(size_t)r * 192 + 64 + ln];
            float4 v2 = x4[(size_t)r * 192 + 128 + ln];
            int rc = r / EPH;
#pragma unroll
            for (int i = 0; i < NMID; ++i) {
                float4 m0 = maf[i * 192 + ln];
                float4 m1 = maf[i * 192 + 64 + ln];
                float4 m2 = maf[i * 192 + 128 + ln];
                float p = m0.x * v0.x + m0.y * v0.y + m0.z * v0.z + m0.w * v0.w
                        + m1.x * v1.x + m1.y * v1.y + m1.z * v1.z + m1.w * v1.w
                        + m2.x * v2.x + m2.y * v2.y + m2.z * v2.z + m2.w * v2.w;
#pragma unroll
                for (int off = 32; off > 0; off >>= 1) p += __shfl_down(p, off, 64);
                if (ln == 0) {
                    float v = (rc == i) ? 0.f : p;
                    ws[OFF_SC + r * NMID + i] = v;
                    scl[(wave * 8 + rr) * NMID + i] = v;
                }
            }
        }
        __syncthreads();
        if (tid < NMID) {
            float m = -1e30f;
            for (int r = 0; r < 32; ++r) m = fmaxf(m, scl[r * NMID + tid]);
            float s = 0.f;
            for (int r = 0; r < 32; ++r) s += expf(scl[r * NMID + tid] - m);
            ws[OFF_SCB + bx * 20 + tid * 2]     = m;
            ws[OFF_SCB + bx * 20 + tid * 2 + 1] = s;
        }
    }
    gbar(bar);

    // ---------------- P3: softmax finalize + PV partials ----------------
    if (bx < 64) {
        float* lm  = lds;          // 160
        float* ls  = lds + 160;    // 160
        float* Mi  = lds + 320;    // 16
        float* Inv = lds + 336;    // 16
        float* p   = lds + 352;    // 1280
        if (tid < 160) {
            int i = tid >> 4, seg = tid & 15;
            float m = -1e30f;
            for (int b = seg * 16; b < seg * 16 + 16; ++b)
                m = fmaxf(m, ws[OFF_SCB + b * 20 + i * 2]);
            float s = 0.f;
            for (int b = seg * 16; b < seg * 16 + 16; ++b)
                s += ws[OFF_SCB + b * 20 + i * 2 + 1] *
                     expf(ws[OFF_SCB + b * 20 + i * 2] - m);
            lm[tid] = m; ls[tid] = s;
        }
        __syncthreads();
        if (tid < NMID) {
            float M = -1e30f;
            for (int g = 0; g < 16; ++g) M = fmaxf(M, lm[tid * 16 + g]);
            float Ssum = 0.f;
            for (int g = 0; g < 16; ++g) Ssum += ls[tid * 16 + g] * expf(lm[tid * 16 + g] - M);
            Mi[tid] = M; Inv[tid] = 1.f / Ssum;
        }
        __syncthreads();
        int r0 = bx * 128;
        for (int t = tid; t < 128 * NMID; t += 256) {
            int i = t % NMID;
            p[t] = expf(ws[OFF_SC + r0 * NMID + t] - Mi[i]) * Inv[i];
        }
        __syncthreads();
        float a0[NMID], a1[NMID], a2[NMID];
#pragma unroll
        for (int i = 0; i < NMID; ++i) { a0[i] = 0.f; a1[i] = 0.f; a2[i] = 0.f; }
        for (int r = 0; r < 128; ++r) {
            const float* xr = x + (size_t)(r0 + r) * D;
            float x0 = xr[tid], x1 = xr[tid + 256], x2 = xr[tid + 512];
#pragma unroll
            for (int i = 0; i < NMID; ++i) {
                float pv = p[r * NMID + i];
                a0[i] += pv * x0; a1[i] += pv * x1; a2[i] += pv * x2;
            }
        }
#pragma unroll
        for (int i = 0; i < NMID; ++i) {
            float* base = ws + OFF_PVP + (bx * NMID + i) * D;
            base[tid]       = a0[i];
            base[tid + 256] = a1[i];
            base[tid + 512] = a2[i];
        }
    }
    gbar(bar);

    // ---------------- P4: (mid + pv) @ W1 -> Y1 ----------------
    if (bx < 48) {
        int kb = bx * 16;
        if (tid < 160) {
            int cl = tid >> 4, k = tid & 15;
            float s = ws[OFF_MID + cl * D + kb + k];
            for (int b = 0; b < 64; ++b)
                s += ws[OFF_PVP + (b * NMID + cl) * D + kb + k];
            lds[tid] = s;
        }
        __syncthreads();
        mm_core<10>(W1, lds, ws + OFF_Y1, kb);
    }
    gbar(bar);

    // ---------------- P5: NM; x_mid; mid2 @ attH -> Z2 ----------------
    if (bx < 48) {
        float* aa  = lds;          // 100
        float* dg  = lds + 100;    // 16
        float* NM  = lds + 128;    // 100
        float* xml = lds + 256;    // 160
        float* mi  = lds + 416;    // 80
        if (tid < 100) {
            float s = 0.f;
#pragma unroll
            for (int sp = 0; sp < 6; ++sp) s += ws[PART_ADJ + tid * 6 + sp];
            aa[tid] = s;
        }
        __syncthreads();
        if (tid < 10) {
            float s = 0.f;
#pragma unroll
            for (int j = 0; j < 10; ++j) s += (tid == j) ? 1.0f : aa[tid * 10 + j];
            dg[tid] = 1.0f / sqrtf(fmaxf(s, 1.0f));
        }
        __syncthreads();
        if (tid < 100) {
            int i = tid / 10, j = tid % 10;
            NM[tid] = dg[i] * ((i == j) ? 1.0f : aa[tid]) * dg[j];
        }
        __syncthreads();
        int kb = bx * 16;
        if (tid < 160) {
            int i = tid >> 4, c = kb + (tid & 15);
            float s = b1[c];
#pragma unroll
            for (int j = 0; j < 10; ++j) s += NM[i * 10 + j] * ws[OFF_Y1 + j * D + c];
            float xm = fmaxf(s, 0.f);
            ws[OFF_XMID + i * D + c] = xm;
            xml[tid] = xm;
        }
        __syncthreads();
        if (tid < 80) {
            int a = tid >> 4, k = tid & 15;
            mi[tid] = xml[(2 * a) * 16 + k] + xml[(2 * a + 1) * 16 + k];
        }
        __syncthreads();
        mm_core<5>(attH, mi, ws + OFF_Z2, kb);
    }
    gbar(bar);

    // ---------------- P6: level-2 attention + out2 @ W2 -> Y2 ----------------
    if (bx < 48) {
        float* s2 = lds;           // 64
        float* P2 = lds + 64;      // 50
        float* mi = lds + 128;     // 80
        int wv = tid >> 6, ln = tid & 63;
        for (int pp = wv; pp < 50; pp += 4) {
            int i = pp / 10, r = pp % 10;
            const float4* za = (const float4*)(ws + OFF_Z2 + i * D);
            const float4* xa = (const float4*)(ws + OFF_XMID + r * D);
            float acc = 0.f;
#pragma unroll
            for (int q = 0; q < 3; ++q) {
                float4 a = za[q * 64 + ln], b = xa[q * 64 + ln];
                acc += a.x * b.x + a.y * b.y + a.z * b.z + a.w * b.w;
            }
#pragma unroll
            for (int off = 32; off > 0; off >>= 1) acc += __shfl_down(acc, off, 64);
            if (ln == 0) s2[pp] = ((r >> 1) == i) ? 0.f : acc;
        }
        __syncthreads();
        if (tid < 5) {
            float mx = -1e30f;
#pragma unroll
            for (int r = 0; r < 10; ++r) mx = fmaxf(mx, s2[tid * 10 + r]);
            float sm = 0.f; float e[10];
#pragma unroll
            for (int r = 0; r < 10; ++r) { e[r] = expf(s2[tid * 10 + r] - mx); sm += e[r]; }
#pragma unroll
            for (int r = 0; r < 10; ++r) P2[tid * 10 + r] = e[r] / sm;
        }
        __syncthreads();
        int kb = bx * 16;
        if (tid < 80) {
            int i = tid >> 4, c = kb + (tid & 15);
            float xm[10];
#pragma unroll
            for (int r = 0; r < 10; ++r) xm[r] = ws[OFF_XMID + r * D + c];
            float o = xm[2 * i] + xm[2 * i + 1];
#pragma unroll
            for (int r = 0; r < 10; ++r) o += P2[i * 10 + r] * xm[r];
            mi[tid] = o;
        }
        __syncthreads();
        mm_core<5>(W2, mi, ws + OFF_Y2, kb);
    }
    gbar(bar);

    // ---------------- P7: NH; out = mean relu(NH @ Y2 + b2) ----------------
    if (bx == 0) {
        float* aa = lds;           // 100
        float* ha = lds + 100;     // 25
        float* dh = lds + 128;     // 8
        float* NH = lds + 136;     // 25
        if (tid < 100) {
            float s = 0.f;
#pragma unroll
            for (int sp = 0; sp < 6; ++sp) s += ws[PART_ADJ + tid * 6 + sp];
            aa[tid] = s;
        }
        __syncthreads();
        if (tid < 25) {
            int a = tid / 5, b = tid % 5;
            ha[tid] = aa[(2 * a) * 10 + 2 * b] + aa[(2 * a) * 10 + 2 * b + 1]
                    + aa[(2 * a + 1) * 10 + 2 * b] + aa[(2 * a + 1) * 10 + 2 * b + 1];
        }
        __syncthreads();
        if (tid < 5) {
            float s = 0.f;
#pragma unroll
            for (int j = 0; j < 5; ++j) s += (tid == j) ? 1.0f : ha[tid * 5 + j];
            dh[tid] = 1.0f / sqrtf(fmaxf(s, 1.0f));
        }
        __syncthreads();
        if (tid < 25) {
            int i = tid / 5, j = tid % 5;
            NH[tid] = dh[i] * ((i == j) ? 1.0f : ha[tid]) * dh[j];
        }
        __syncthreads();
#pragma unroll
        for (int g = 0; g < 3; ++g) {
            int c = tid + g * 256;
            float y[5];
#pragma unroll
            for (int j = 0; j < 5; ++j) y[j] = ws[OFF_Y2 + j * D + c];
            float bias = b2[c];
            float s = 0.f;
#pragma unroll
            for (int i = 0; i < 5; ++i) {
                float v = bias;
#pragma unroll
                for (int j = 0; j < 5; ++j) v += NH[i * 5 + j] * y[j];
                s += fmaxf(v, 0.f);
            }
            out[c] = s * 0.2f;
        }
    }
}

// ---------------- launcher ----------------
extern "C" void kernel_launch(void* const* d_in, const int* in_sizes, int n_in,
                              void* d_out, int out_size, void* d_ws, size_t ws_size,
                              hipStream_t stream) {
    const float* x    = (const float*)d_in[0];
    const float* adj  = (const float*)d_in[1];
    const float* attL = (const float*)d_in[2];
    const float* W1   = (const float*)d_in[3];
    const float* b1   = (const float*)d_in[4];
    const float* attH = (const float*)d_in[5];
    const float* W2   = (const float*)d_in[6];
    const float* b2   = (const float*)d_in[7];
    float* ws  = (float*)d_ws;
    float* out = (float*)d_out;

    k_init<<<1, 64, 0, stream>>>(ws);
    k_main<<<NB, 256, 0, stream>>>(adj, x, attL, W1, b1, attH, W2, b2, ws, out);
}

// Round 5
// 193.786 us; speedup vs baseline: 6.7215x; 6.7215x over previous
//
#include <hip/hip_runtime.h>

// ---------------- problem constants ----------------
constexpr int S    = 8192;
constexpr int D    = 768;
constexpr int NMID = 10;
constexpr int EPH  = 820;    // ceil(8192/10); 820 = 4*205 -> no float4 straddle
constexpr int ASPLIT = 184;  // adjacency row-splits per row-cluster
constexpr int MSPLIT = 20;   // x column-sum row-splits per cluster
constexpr int N_ADJ_IT = 10 * ASPLIT;            // 1840
constexpr int N_MID_IT = 10 * MSPLIT;            // 200
constexpr int IT_ZERO  = N_ADJ_IT + N_MID_IT;    // 2040
constexpr int N_IT     = IT_ZERO + 1;            // 2041
constexpr int NB1 = 1024;

// ---------------- workspace layout (float element offsets) ----------------
constexpr int PART_ADJ = 0;                      // 1840*10 = 18400
constexpr int PART_MID = 18432;                  // 20*10*768 = 153600
constexpr int OFF_AA   = PART_MID + 153600;      // 172032: 100 (reduced mid_adj)
constexpr int OFF_MATT = 172160;                 // 7680  mid @ attL (complete)
constexpr int OFF_MREP = OFF_MATT + 7680;        // 179840: 7680 P@x (atomic, zeroed)
constexpr int OFF_XMID = OFF_MREP + 7680;        // 187520: 7680
constexpr int OFF_MID2 = OFF_XMID + 7680;        // 195200: 3840
constexpr int OFF_Z2   = OFF_MID2 + 3840;        // 199040: 3840
constexpr int OFF_SC   = OFF_Z2 + 3840;          // 202880: 81920 scores [8192][10]
constexpr int OFF_SCB  = OFF_SC + 81920;         // 284800: 512*20 softmax stats

// full-K col-slice matmul: outS[i][c] = sum_k inL[i*768+k] * W[k][c0+c], c<16
template <int NR>
__device__ __forceinline__ void fullk_slice(const float* __restrict__ W,
                                            const float* inL, float* red,
                                            float* outS, int c0) {
    int tid = threadIdx.x;
    int c = tid & 15, ks = tid >> 4;        // 16 c x 16 k-splits
    float acc[NR];
#pragma unroll
    for (int i = 0; i < NR; ++i) acc[i] = 0.f;
    int kb = ks * 48;
    for (int kk = 0; kk < 48; ++kk) {
        int k = kb + kk;
        float w = W[(size_t)k * D + c0 + c];
#pragma unroll
        for (int i = 0; i < NR; ++i) acc[i] += inL[i * D + k] * w;
    }
#pragma unroll
    for (int i = 0; i < NR; ++i) red[(ks * NR + i) * 16 + c] = acc[i];
    __syncthreads();
    if (tid < NR * 16) {
        int i = tid >> 4, cc = tid & 15;
        float s = 0.f;
#pragma unroll
        for (int k2 = 0; k2 < 16; ++k2) s += red[(k2 * NR + i) * 16 + cc];
        outS[i * 16 + cc] = s;
    }
    __syncthreads();
}

// ---- K1: big HBM pass. 2041 items grid-strided over 1024 blocks ----
// adj item: full-width rows, 10 col-cluster sums via static slot->j buckets
__global__ __launch_bounds__(256) void k1(const float* __restrict__ A,
                                          const float* __restrict__ x,
                                          float* __restrict__ ws) {
    __shared__ float bucket[2560];   // [10][256]
    __shared__ float red2[160];
    int tid = threadIdx.x;
    for (int it = blockIdx.x; it < N_IT; it += NB1) {
        if (it < N_ADJ_IT) {
            int i = it / ASPLIT, s = it % ASPLIT;
            int r0 = i * EPH, nr = min(EPH, S - r0);
            int rs0 = r0 + nr * s / ASPLIT, rs1 = r0 + nr * (s + 1) / ASPLIT;
            float acc[8];
#pragma unroll
            for (int t = 0; t < 8; ++t) acc[t] = 0.f;
            for (int r = rs0; r < rs1; ++r) {
                const float4* row = (const float4*)(A + (size_t)r * S);
#pragma unroll
                for (int t = 0; t < 8; ++t) {
                    float4 v = row[tid + 256 * t];
                    acc[t] += (v.x + v.y) + (v.z + v.w);
                }
            }
            for (int t = tid; t < 2560; t += 256) bucket[t] = 0.f;
            __syncthreads();
#pragma unroll
            for (int t = 0; t < 8; ++t) {
                int j = (tid + 256 * t) / 205;   // col-cluster of this slot
                bucket[j * 256 + tid] += acc[t];
            }
            __syncthreads();
            if (tid < 160) {
                int j = tid >> 4, seg = tid & 15;
                float sm = 0.f;
#pragma unroll
                for (int u = 0; u < 16; ++u) sm += bucket[j * 256 + seg * 16 + u];
                red2[tid] = sm;
            }
            __syncthreads();
            if (tid < 10) {
                float sm = 0.f;
#pragma unroll
                for (int g = 0; g < 16; ++g) sm += red2[tid * 16 + g];
                ws[PART_ADJ + it * 10 + tid] = sm;
            }
            __syncthreads();
        } else if (it < IT_ZERO) {
            int m = it - N_ADJ_IT;
            int cl = m / MSPLIT, sp = m % MSPLIT;
            int r0 = cl * EPH, nr = min(EPH, S - r0);
            int rs0 = r0 + nr * sp / MSPLIT, rs1 = r0 + nr * (sp + 1) / MSPLIT;
            float a0 = 0.f, a1 = 0.f, a2 = 0.f;
            for (int r = rs0; r < rs1; ++r) {
                const float* xr = x + (size_t)r * D;
                a0 += xr[tid]; a1 += xr[tid + 256]; a2 += xr[tid + 512];
            }
            int base = PART_MID + (sp * NMID + cl) * D;
            ws[base + tid] = a0; ws[base + tid + 256] = a1; ws[base + tid + 512] = a2;
        } else {
            for (int t = tid; t < 7680; t += 256) ws[OFF_MREP + t] = 0.f;
        }
    }
}

// ---- K2: blocks 0..47: MATT = mid @ attL (full-K col-slice);
//          blocks 48,49: reduce adjacency partials -> AA[100] ----
__global__ __launch_bounds__(256) void k2(const float* __restrict__ attL,
                                          float* __restrict__ ws) {
    int bx = blockIdx.x, tid = threadIdx.x;
    if (bx < 48) {
        __shared__ float midL[7680];
        __shared__ float red[2560];
        __shared__ float outS[160];
        for (int t = tid; t < 7680; t += 256) {
            int cl = t / D, k = t - cl * D;
            float s = 0.f;
#pragma unroll
            for (int sp = 0; sp < MSPLIT; ++sp)
                s += ws[PART_MID + (sp * NMID + cl) * D + k];
            midL[t] = s;
        }
        __syncthreads();
        fullk_slice<10>(attL, midL, red, outS, bx * 16);
        if (tid < 160) ws[OFF_MATT + (tid >> 4) * D + bx * 16 + (tid & 15)] = outS[tid];
    } else {
        __shared__ float ared[200];
        int base = (bx - 48) * 50;
        if (tid < 200) {
            int p = base + (tid >> 2), q = tid & 3;
            int i = p / 10, j = p % 10;
            float s = 0.f;
            for (int t2 = q * 46; t2 < q * 46 + 46; ++t2)
                s += ws[PART_ADJ + (i * ASPLIT + t2) * 10 + j];
            ared[tid] = s;
        }
        __syncthreads();
        if (tid < 50) {
            int lb = (tid + base - base) * 4;  // tid*4
            ws[OFF_AA + base + tid] = ared[lb] + ared[lb + 1] + ared[lb + 2] + ared[lb + 3];
        }
    }
}

// ---- K3: scores + per-block softmax stats; 512 blocks x 16 rows ----
__global__ __launch_bounds__(256) void k3(const float* __restrict__ x,
                                          float* __restrict__ ws) {
    __shared__ float ma[7680];
    __shared__ float scl[160];
    int tid = threadIdx.x, bx = blockIdx.x;
    for (int t = tid; t < 7680; t += 256) ma[t] = ws[OFF_MATT + t];
    __syncthreads();
    const float4* maf = (const float4*)ma;
    const float4* x4  = (const float4*)x;
    int wave = tid >> 6, ln = tid & 63;
    int rbase = bx * 16 + wave * 4;
    for (int rr = 0; rr < 4; ++rr) {
        int r = rbase + rr;
        float4 v0 = x4[(size_t)r * 192 + ln];
        float4 v1 = x4[(size_t)r * 192 + 64 + ln];
        float4 v2 = x4[(size_t)r * 192 + 128 + ln];
        int rc = r / EPH;
#pragma unroll
        for (int i = 0; i < NMID; ++i) {
            float4 m0 = maf[i * 192 + ln];
            float4 m1 = maf[i * 192 + 64 + ln];
            float4 m2 = maf[i * 192 + 128 + ln];
            float p = m0.x * v0.x + m0.y * v0.y + m0.z * v0.z + m0.w * v0.w
                    + m1.x * v1.x + m1.y * v1.y + m1.z * v1.z + m1.w * v1.w
                    + m2.x * v2.x + m2.y * v2.y + m2.z * v2.z + m2.w * v2.w;
#pragma unroll
            for (int off = 32; off > 0; off >>= 1) p += __shfl_down(p, off, 64);
            if (ln == 0) {
                float v = (rc == i) ? 0.f : p;
                ws[OFF_SC + r * NMID + i] = v;
                scl[(wave * 4 + rr) * NMID + i] = v;
            }
        }
    }
    __syncthreads();
    if (tid < NMID) {
        float m = -1e30f;
        for (int r2 = 0; r2 < 16; ++r2) m = fmaxf(m, scl[r2 * NMID + tid]);
        float s = 0.f;
        for (int r2 = 0; r2 < 16; ++r2) s += expf(scl[r2 * NMID + tid] - m);
        ws[OFF_SCB + bx * 20 + tid * 2]     = m;
        ws[OFF_SCB + bx * 20 + tid * 2 + 1] = s;
    }
}

// ---- K4: softmax finalize + P@x partial-accumulate (atomic) ; 128 blocks x 64 rows ----
__global__ __launch_bounds__(256) void k4(const float* __restrict__ x,
                                          float* __restrict__ ws) {
    __shared__ float lm[160], ls[160], Mi[10], Inv[10], p[640];
    int tid = threadIdx.x, bx = blockIdx.x;
    if (tid < 160) {
        int i = tid >> 4, seg = tid & 15;
        float m = -1e30f;
        for (int b = seg * 32; b < seg * 32 + 32; ++b)
            m = fmaxf(m, ws[OFF_SCB + b * 20 + i * 2]);
        float s = 0.f;
        for (int b = seg * 32; b < seg * 32 + 32; ++b)
            s += ws[OFF_SCB + b * 20 + i * 2 + 1] *
                 expf(ws[OFF_SCB + b * 20 + i * 2] - m);
        lm[tid] = m; ls[tid] = s;
    }
    __syncthreads();
    if (tid < NMID) {
        float M = -1e30f;
        for (int g = 0; g < 16; ++g) M = fmaxf(M, lm[tid * 16 + g]);
        float Ss = 0.f;
        for (int g = 0; g < 16; ++g) Ss += ls[tid * 16 + g] * expf(lm[tid * 16 + g] - M);
        Mi[tid] = M; Inv[tid] = 1.f / Ss;
    }
    __syncthreads();
    int r0 = bx * 64;
    for (int t = tid; t < 640; t += 256) {
        int i = t % NMID;
        p[t] = expf(ws[OFF_SC + r0 * NMID + t] - Mi[i]) * Inv[i];
    }
    __syncthreads();
    float a0[NMID], a1[NMID], a2[NMID];
#pragma unroll
    for (int i = 0; i < NMID; ++i) { a0[i] = 0.f; a1[i] = 0.f; a2[i] = 0.f; }
    for (int r = 0; r < 64; ++r) {
        const float* xr = x + (size_t)(r0 + r) * D;
        float x0 = xr[tid], x1 = xr[tid + 256], x2 = xr[tid + 512];
#pragma unroll
        for (int i = 0; i < NMID; ++i) {
            float pv = p[r * NMID + i];
            a0[i] += pv * x0; a1[i] += pv * x1; a2[i] += pv * x2;
        }
    }
#pragma unroll
    for (int i = 0; i < NMID; ++i) {
        atomicAdd(&ws[OFF_MREP + i * D + tid],       a0[i]);
        atomicAdd(&ws[OFF_MREP + i * D + tid + 256], a1[i]);
        atomicAdd(&ws[OFF_MREP + i * D + tid + 512], a2[i]);
    }
}

// ---- K5: inmid = mid + mrep; NM; xmid = relu(NM@(inmid@W1) + b1); mid2 ----
__global__ __launch_bounds__(256) void k5(const float* __restrict__ W1,
                                          const float* __restrict__ b1,
                                          float* __restrict__ ws) {
    __shared__ float inmid[7680];
    __shared__ float red[2560];
    __shared__ float Y1s[160];
    __shared__ float aaL[100], dg[10], NM[100], xml[160];
    int tid = threadIdx.x, c0 = blockIdx.x * 16;
    for (int t = tid; t < 7680; t += 256) {
        int cl = t / D, k = t - cl * D;
        float s = ws[OFF_MREP + t];
#pragma unroll
        for (int sp = 0; sp < MSPLIT; ++sp)
            s += ws[PART_MID + (sp * NMID + cl) * D + k];
        inmid[t] = s;
    }
    if (tid < 100) aaL[tid] = ws[OFF_AA + tid];
    __syncthreads();
    fullk_slice<10>(W1, inmid, red, Y1s, c0);
    if (tid < 10) {
        float s = 0.f;
#pragma unroll
        for (int j = 0; j < 10; ++j) s += (tid == j) ? 1.f : aaL[tid * 10 + j];
        dg[tid] = 1.f / sqrtf(fmaxf(s, 1.f));
    }
    __syncthreads();
    if (tid < 100) {
        int i = tid / 10, j = tid % 10;
        NM[tid] = dg[i] * ((i == j) ? 1.f : aaL[tid]) * dg[j];
    }
    __syncthreads();
    if (tid < 160) {
        int i = tid >> 4, cc = tid & 15;
        float v = b1[c0 + cc];
#pragma unroll
        for (int j = 0; j < 10; ++j) v += NM[i * 10 + j] * Y1s[j * 16 + cc];
        float xm = fmaxf(v, 0.f);
        ws[OFF_XMID + i * D + c0 + cc] = xm;
        xml[tid] = xm;
    }
    __syncthreads();
    if (tid < 80) {
        int a = tid >> 4, cc = tid & 15;
        ws[OFF_MID2 + a * D + c0 + cc] = xml[(2 * a) * 16 + cc] + xml[(2 * a + 1) * 16 + cc];
    }
}

// ---- K6: Z2 = mid2 @ attH (full-K col-slice) ----
__global__ __launch_bounds__(256) void k6(const float* __restrict__ attH,
                                          float* __restrict__ ws) {
    __shared__ float m2L[3840];
    __shared__ float red[1280];
    __shared__ float z2s[80];
    int tid = threadIdx.x, c0 = blockIdx.x * 16;
    for (int t = tid; t < 3840; t += 256) m2L[t] = ws[OFF_MID2 + t];
    __syncthreads();
    fullk_slice<5>(attH, m2L, red, z2s, c0);
    if (tid < 80) ws[OFF_Z2 + (tid >> 4) * D + c0 + (tid & 15)] = z2s[tid];
}

// ---- K7: scores2+softmax (redundant/block); out2; Y2 slice; NH; out slice ----
__global__ __launch_bounds__(256) void k7(const float* __restrict__ W2,
                                          const float* __restrict__ b2,
                                          float* __restrict__ ws,
                                          float* __restrict__ out) {
    __shared__ float out2L[3840];
    __shared__ float red[1280];
    __shared__ float Y2s[80];
    __shared__ float sred[200], s2[50], P2[50];
    __shared__ float aaL[100], ha[25], dh[5], NH[25];
    int tid = threadIdx.x, c0 = blockIdx.x * 16;
    if (tid < 200) {
        int pp = tid >> 2, q = tid & 3;
        int i = pp / 10, r = pp % 10;
        const float* z  = ws + OFF_Z2 + i * D;
        const float* xm = ws + OFF_XMID + r * D;
        float s = 0.f;
        for (int c = q * 192; c < q * 192 + 192; ++c) s += z[c] * xm[c];
        sred[tid] = s;
    }
    if (tid < 100) aaL[tid] = ws[OFF_AA + tid];
    __syncthreads();
    if (tid < 50) {
        int i = tid / 10, r = tid % 10;
        float v = sred[tid * 4] + sred[tid * 4 + 1] + sred[tid * 4 + 2] + sred[tid * 4 + 3];
        s2[tid] = ((r >> 1) == i) ? 0.f : v;
    }
    __syncthreads();
    if (tid < 5) {
        float mx = -1e30f;
#pragma unroll
        for (int r = 0; r < 10; ++r) mx = fmaxf(mx, s2[tid * 10 + r]);
        float sm = 0.f;
        float e[10];
#pragma unroll
        for (int r = 0; r < 10; ++r) { e[r] = expf(s2[tid * 10 + r] - mx); sm += e[r]; }
#pragma unroll
        for (int r = 0; r < 10; ++r) P2[tid * 10 + r] = e[r] / sm;
    }
    __syncthreads();
    for (int t = tid; t < 3840; t += 256) {
        int i = t / D, k = t - i * D;
        float v = ws[OFF_MID2 + t];
#pragma unroll
        for (int r = 0; r < 10; ++r) v += P2[i * 10 + r] * ws[OFF_XMID + r * D + k];
        out2L[t] = v;
    }
    __syncthreads();
    fullk_slice<5>(W2, out2L, red, Y2s, c0);
    if (tid < 25) {
        int a = tid / 5, b = tid % 5;
        ha[tid] = aaL[(2 * a) * 10 + 2 * b] + aaL[(2 * a) * 10 + 2 * b + 1]
                + aaL[(2 * a + 1) * 10 + 2 * b] + aaL[(2 * a + 1) * 10 + 2 * b + 1];
    }
    __syncthreads();
    if (tid < 5) {
        float s = 0.f;
#pragma unroll
        for (int j = 0; j < 5; ++j) s += (tid == j) ? 1.f : ha[tid * 5 + j];
        dh[tid] = 1.f / sqrtf(fmaxf(s, 1.f));
    }
    __syncthreads();
    if (tid < 25) {
        int i = tid / 5, j = tid % 5;
        NH[tid] = dh[i] * ((i == j) ? 1.f : ha[tid]) * dh[j];
    }
    __syncthreads();
    if (tid < 16) {
        int c = c0 + tid;
        float bias = b2[c];
        float s = 0.f;
#pragma unroll
        for (int i = 0; i < 5; ++i) {
            float v = bias;
#pragma unroll
            for (int j = 0; j < 5; ++j) v += NH[i * 5 + j] * Y2s[j * 16 + tid];
            s += fmaxf(v, 0.f);
        }
        out[c] = s * 0.2f;
    }
}

// ---------------- launcher ----------------
extern "C" void kernel_launch(void* const* d_in, const int* in_sizes, int n_in,
                              void* d_out, int out_size, void* d_ws, size_t ws_size,
                              hipStream_t stream) {
    const float* x    = (const float*)d_in[0];
    const float* adj  = (const float*)d_in[1];
    const float* attL = (const float*)d_in[2];
    const float* W1   = (const float*)d_in[3];
    const float* b1   = (const float*)d_in[4];
    const float* attH = (const float*)d_in[5];
    const float* W2   = (const float*)d_in[6];
    const float* b2   = (const float*)d_in[7];
    float* ws  = (float*)d_ws;
    float* out = (float*)d_out;

    k1<<<NB1, 256, 0, stream>>>(adj, x, ws);
    k2<<<50,  256, 0, stream>>>(attL, ws);
    k3<<<512, 256, 0, stream>>>(x, ws);
    k4<<<128, 256, 0, stream>>>(x, ws);
    k5<<<48,  256, 0, stream>>>(W1, b1, ws);
    k6<<<48,  256, 0, stream>>>(attH, ws);
    k7<<<48,  256, 0, stream>>>(W2, b2, ws, out);
}

// Round 6
// 177.766 us; speedup vs baseline: 7.3272x; 1.0901x over previous
//
#include <hip/hip_runtime.h>

// ---------------- problem constants ----------------
constexpr int S    = 8192;
constexpr int D    = 768;
constexpr int NMID = 10;
constexpr int EPH  = 820;   // ceil(8192/10); 820 = 4*205 -> no float4 straddle
constexpr int TAILB = 48;   // tail kernel block count (one per 16-col slice)

// ---------------- workspace layout (float element offsets) ----------------
constexpr int PART_ADJ = 0;        // 3200 adjacency partials [pair][split32]
constexpr int PART_MID = 3200;     // 8*10*768 = 61440 mid partials [sp][cl][col]
constexpr int OFF_Y1   = 64640;    // 7680 (atomic, zeroed in K1)
constexpr int OFF_Z2   = 72320;    // 3840 (atomic, zeroed in K1)
constexpr int OFF_MATT = 76160;    // 7680 mid @ attL
constexpr int OFF_XMID = 83840;    // 7680
constexpr int OFF_MID2 = 91520;    // 3840
constexpr int OFF_SCB  = 95360;    // 128*20 per-block softmax stats (m, sumexp)
constexpr int OFF_PVP  = 97920;    // 128*10*768 unnormalized PV partials
constexpr int OFF_BAR  = 1081344;  // barrier: cnt @u32[0], gen @u32[32]

// ---------------- adjacency partial: 100 pairs x 32 row-splits ----------------
__device__ __forceinline__ void adj_partial(const float* __restrict__ A,
                                            float* __restrict__ ws, int item) {
    __shared__ float wred[4];
    int p = item >> 5, s = item & 31;
    int i = p / 10, j = p % 10;
    int r0 = i * EPH, nr = min(EPH, S - r0);
    int c0 = j * EPH, nc = min(EPH, S - c0);
    int rs0 = r0 + (nr * s) / 32, rs1 = r0 + (nr * (s + 1)) / 32;
    int nc4 = nc >> 2;
    int tid = threadIdx.x;
    float acc = 0.f;
    for (int r = rs0; r < rs1; ++r) {
        const float4* row = (const float4*)(A + (size_t)r * S + c0);
        if (tid < nc4) {
            float4 v = row[tid];
            acc += (v.x + v.y) + (v.z + v.w);
        }
    }
#pragma unroll
    for (int off = 32; off > 0; off >>= 1) acc += __shfl_down(acc, off, 64);
    int ln = tid & 63, wv = tid >> 6;
    if (ln == 0) wred[wv] = acc;
    __syncthreads();
    if (tid == 0) ws[PART_ADJ + item] = (wred[0] + wred[1]) + (wred[2] + wred[3]);
}

// mid column-sum partials: 10 cl x 3 cc x 8 sp = 240 items
__device__ __forceinline__ void mid_partial(const float* __restrict__ x,
                                            float* __restrict__ ws, int item) {
    int cl = item / 24, rem = item % 24;
    int cc = rem >> 3, sp = rem & 7;
    int r0 = cl * EPH, nr = min(EPH, S - r0);
    int rs0 = r0 + (nr * sp) / 8, rs1 = r0 + (nr * (sp + 1)) / 8;
    int c = cc * 256 + threadIdx.x;
    float acc = 0.f;
    for (int r = rs0; r < rs1; ++r) acc += x[(size_t)r * D + c];
    ws[PART_MID + (sp * NMID + cl) * D + c] = acc;
}

// out[NR][768] += mi[NR][16] @ W[kb:kb+16][768]  (atomic k-split)
template <int NR>
__device__ __forceinline__ void mm_core(const float* __restrict__ W,
                                        const float* mi,
                                        float* __restrict__ out, int kb) {
    int c = threadIdx.x;
    float a0[NR], a1[NR], a2[NR];
#pragma unroll
    for (int i = 0; i < NR; ++i) { a0[i] = 0.f; a1[i] = 0.f; a2[i] = 0.f; }
    for (int kk = 0; kk < 16; ++kk) {
        const float* wr = W + (size_t)(kb + kk) * D;
        float w0 = wr[c], w1 = wr[c + 256], w2 = wr[c + 512];
#pragma unroll
        for (int i = 0; i < NR; ++i) {
            float m = mi[i * 16 + kk];
            a0[i] += m * w0; a1[i] += m * w1; a2[i] += m * w2;
        }
    }
#pragma unroll
    for (int i = 0; i < NR; ++i) {
        atomicAdd(&out[i * D + c],       a0[i]);
        atomicAdd(&out[i * D + c + 256], a1[i]);
        atomicAdd(&out[i * D + c + 512], a2[i]);
    }
}

// full-K col-slice matmul: outS[i][c] = sum_k inL[i*768+k] * W[k][c0+c]
template <int NR>
__device__ __forceinline__ void fullk_slice(const float* __restrict__ W,
                                            const float* inL, float* red,
                                            float* outS, int c0) {
    int tid = threadIdx.x;
    int c = tid & 15, ks = tid >> 4;
    float acc[NR];
#pragma unroll
    for (int i = 0; i < NR; ++i) acc[i] = 0.f;
    int kb = ks * 48;
    for (int kk = 0; kk < 48; ++kk) {
        int k = kb + kk;
        float w = W[(size_t)k * D + c0 + c];
#pragma unroll
        for (int i = 0; i < NR; ++i) acc[i] += inL[i * D + k] * w;
    }
#pragma unroll
    for (int i = 0; i < NR; ++i) red[(ks * NR + i) * 16 + c] = acc[i];
    __syncthreads();
    if (tid < NR * 16) {
        int i = tid >> 4, cc = tid & 15;
        float s = 0.f;
#pragma unroll
        for (int k2 = 0; k2 < 16; ++k2) s += red[(k2 * NR + i) * 16 + cc];
        outS[i * 16 + cc] = s;
    }
    __syncthreads();
}

// ---------------- device barrier for the 48-block tail ----------------
__device__ __forceinline__ void gbar(unsigned* bar) {
    __syncthreads();
    if (threadIdx.x == 0) {
        __threadfence();
        unsigned g = __hip_atomic_load(bar + 32, __ATOMIC_RELAXED, __HIP_MEMORY_SCOPE_AGENT);
        unsigned a = __hip_atomic_fetch_add(bar, 1u, __ATOMIC_ACQ_REL, __HIP_MEMORY_SCOPE_AGENT);
        if (a == (unsigned)(TAILB - 1)) {
            __hip_atomic_store(bar, 0u, __ATOMIC_RELAXED, __HIP_MEMORY_SCOPE_AGENT);
            __hip_atomic_fetch_add(bar + 32, 1u, __ATOMIC_RELEASE, __HIP_MEMORY_SCOPE_AGENT);
        } else {
            while (__hip_atomic_load(bar + 32, __ATOMIC_ACQUIRE, __HIP_MEMORY_SCOPE_AGENT) == g)
                __builtin_amdgcn_s_sleep(8);
        }
        __threadfence();
    }
    __syncthreads();
}

// ---- K1: adj items [0,1280) + mid partials (240) + zero Y1/Z2/bar ----
__global__ __launch_bounds__(256) void k1(const float* __restrict__ A,
                                          const float* __restrict__ x,
                                          float* __restrict__ ws) {
    int bx = blockIdx.x, tid = threadIdx.x;
    if (bx < 1280) adj_partial(A, ws, bx);
    else if (bx < 1520) mid_partial(x, ws, bx - 1280);
    else {
        int b = bx - 1520;   // 0..2
        for (int t = b * 256 + tid; t < 11520; t += 768) ws[OFF_Y1 + t] = 0.f;
        if (b == 0 && tid < 64) ((unsigned*)(ws + OFF_BAR))[tid] = 0u;
    }
}

// ---- K2: MATT = mid @ attL (48 blocks) + adj items [1280,2240) ----
__global__ __launch_bounds__(256) void k2(const float* __restrict__ attL,
                                          const float* __restrict__ A,
                                          float* __restrict__ ws) {
    int bx = blockIdx.x, tid = threadIdx.x;
    if (bx >= 48) { adj_partial(A, ws, 1280 + bx - 48); return; }
    __shared__ float midL[7680];
    __shared__ float red[2560];
    __shared__ float outS[160];
    for (int t = tid; t < 7680; t += 256) {
        int cl = t / D, k = t - cl * D;
        float s = 0.f;
#pragma unroll
        for (int sp = 0; sp < 8; ++sp)
            s += ws[PART_MID + (sp * NMID + cl) * D + k];
        midL[t] = s;
    }
    __syncthreads();
    fullk_slice<10>(attL, midL, red, outS, bx * 16);
    if (tid < 160) ws[OFF_MATT + (tid >> 4) * D + bx * 16 + (tid & 15)] = outS[tid];
}

// ---- K3: scores + local softmax stats + unnormalized PV partials
//          (128 blocks x 64 rows) + adj items [2240,3200) ----
__global__ __launch_bounds__(256) void k3(const float* __restrict__ x,
                                          const float* __restrict__ A,
                                          float* __restrict__ ws) {
    int bx = blockIdx.x, tid = threadIdx.x;
    if (bx >= 128) { adj_partial(A, ws, 2240 + bx - 128); return; }
    __shared__ float ma[7680];    // MATT
    __shared__ float sl[640];     // scores [64][10] -> weights in place
    __shared__ float mloc[10];
    for (int t = tid; t < 7680; t += 256) ma[t] = ws[OFF_MATT + t];
    __syncthreads();
    const float4* maf = (const float4*)ma;
    const float4* x4  = (const float4*)x;
    int wave = tid >> 6, ln = tid & 63;
    int r0 = bx * 64;
    for (int rr = 0; rr < 16; ++rr) {
        int rl = wave * 16 + rr;
        int r = r0 + rl;
        float4 v0 = x4[(size_t)r * 192 + ln];
        float4 v1 = x4[(size_t)r * 192 + 64 + ln];
        float4 v2 = x4[(size_t)r * 192 + 128 + ln];
        int rc = r / EPH;
#pragma unroll
        for (int i = 0; i < NMID; ++i) {
            float4 m0 = maf[i * 192 + ln];
            float4 m1 = maf[i * 192 + 64 + ln];
            float4 m2 = maf[i * 192 + 128 + ln];
            float p = m0.x * v0.x + m0.y * v0.y + m0.z * v0.z + m0.w * v0.w
                    + m1.x * v1.x + m1.y * v1.y + m1.z * v1.z + m1.w * v1.w
                    + m2.x * v2.x + m2.y * v2.y + m2.z * v2.z + m2.w * v2.w;
#pragma unroll
            for (int off = 32; off > 0; off >>= 1) p += __shfl_down(p, off, 64);
            if (ln == 0) sl[rl * NMID + i] = (rc == i) ? 0.f : p;
        }
    }
    __syncthreads();
    if (tid < NMID) {
        float m = -1e30f;
        for (int r = 0; r < 64; ++r) m = fmaxf(m, sl[r * NMID + tid]);
        float s = 0.f;
        for (int r = 0; r < 64; ++r) s += expf(sl[r * NMID + tid] - m);
        mloc[tid] = m;
        ws[OFF_SCB + bx * 20 + tid * 2]     = m;
        ws[OFF_SCB + bx * 20 + tid * 2 + 1] = s;
    }
    __syncthreads();
    for (int t = tid; t < 640; t += 256) sl[t] = expf(sl[t] - mloc[t % NMID]);
    __syncthreads();
    float a0[NMID], a1[NMID], a2[NMID];
#pragma unroll
    for (int i = 0; i < NMID; ++i) { a0[i] = 0.f; a1[i] = 0.f; a2[i] = 0.f; }
    for (int r = 0; r < 64; ++r) {
        const float* xr = x + (size_t)(r0 + r) * D;
        float x0 = xr[tid], x1 = xr[tid + 256], x2 = xr[tid + 512];
#pragma unroll
        for (int i = 0; i < NMID; ++i) {
            float w = sl[r * NMID + i];
            a0[i] += w * x0; a1[i] += w * x1; a2[i] += w * x2;
        }
    }
#pragma unroll
    for (int i = 0; i < NMID; ++i) {
        float* base = ws + OFF_PVP + (bx * NMID + i) * D;
        base[tid]       = a0[i];
        base[tid + 256] = a1[i];
        base[tid + 512] = a2[i];
    }
}

// ---- K4 tail: 48 blocks, 3 phases, 2 device barriers ----
__global__ __launch_bounds__(256) void k4(const float* __restrict__ W1,
                                          const float* __restrict__ b1,
                                          const float* __restrict__ attH,
                                          const float* __restrict__ W2,
                                          const float* __restrict__ b2,
                                          float* __restrict__ ws,
                                          float* __restrict__ out) {
    __shared__ float lm[160], ls[160], Mi[16], Zi[16];
    __shared__ float wts[1280];            // e^{m_b - M_i} / Z_i
    __shared__ float mi[160];
    __shared__ float aa[100], dg[16], NM[100], xml[160], mi2[80];
    __shared__ float sred[200], s2l[64], P2[50];
    __shared__ float out2L[3840], red[1280], Y2s[80];
    __shared__ float ha[32], dh[8], NH[32];
    unsigned* bar = (unsigned*)(ws + OFF_BAR);
    int bx = blockIdx.x, tid = threadIdx.x;
    int kb = bx * 16;

    // ---- phase A: global softmax stats; inmid slice; Y1 += inmid@W1 ----
    if (tid < 160) {
        int i = tid >> 4, seg = tid & 15;
        float m = -1e30f;
        for (int b = seg * 8; b < seg * 8 + 8; ++b)
            m = fmaxf(m, ws[OFF_SCB + b * 20 + i * 2]);
        float s = 0.f;
        for (int b = seg * 8; b < seg * 8 + 8; ++b)
            s += ws[OFF_SCB + b * 20 + i * 2 + 1] *
                 expf(ws[OFF_SCB + b * 20 + i * 2] - m);
        lm[tid] = m; ls[tid] = s;
    }
    __syncthreads();
    if (tid < NMID) {
        float M = -1e30f;
        for (int g = 0; g < 16; ++g) M = fmaxf(M, lm[tid * 16 + g]);
        float Z = 0.f;
        for (int g = 0; g < 16; ++g) Z += ls[tid * 16 + g] * expf(lm[tid * 16 + g] - M);
        Mi[tid] = M; Zi[tid] = 1.f / Z;
    }
    __syncthreads();
    for (int t = tid; t < 1280; t += 256) {
        int b = t / NMID, i = t % NMID;
        wts[t] = expf(ws[OFF_SCB + b * 20 + i * 2] - Mi[i]) * Zi[i];
    }
    __syncthreads();
    if (tid < 160) {
        int i = tid >> 4, k = kb + (tid & 15);
        float s = 0.f;
#pragma unroll
        for (int sp = 0; sp < 8; ++sp)
            s += ws[PART_MID + (sp * NMID + i) * D + k];
        for (int b = 0; b < 128; ++b)
            s += wts[b * NMID + i] * ws[OFF_PVP + (b * NMID + i) * D + k];
        mi[tid] = s;
    }
    __syncthreads();
    mm_core<10>(W1, mi, ws + OFF_Y1, kb);

    gbar(bar);

    // ---- phase B: NM; XMID col-slice; MID2; Z2 += mid2@attH ----
    if (tid < 100) {
        float s = 0.f;
#pragma unroll
        for (int sp = 0; sp < 32; ++sp) s += ws[PART_ADJ + tid * 32 + sp];
        aa[tid] = s;
    }
    __syncthreads();
    if (tid < 10) {
        float s = 0.f;
#pragma unroll
        for (int j = 0; j < 10; ++j) s += (tid == j) ? 1.f : aa[tid * 10 + j];
        dg[tid] = 1.f / sqrtf(fmaxf(s, 1.f));
    }
    __syncthreads();
    if (tid < 100) {
        int i = tid / 10, j = tid % 10;
        NM[tid] = dg[i] * ((i == j) ? 1.f : aa[tid]) * dg[j];
    }
    __syncthreads();
    if (tid < 160) {
        int i = tid >> 4, c = kb + (tid & 15);
        float v = b1[c];
#pragma unroll
        for (int j = 0; j < 10; ++j) v += NM[i * 10 + j] * ws[OFF_Y1 + j * D + c];
        float xm = fmaxf(v, 0.f);
        ws[OFF_XMID + i * D + c] = xm;
        xml[tid] = xm;
    }
    __syncthreads();
    if (tid < 80) {
        int a = tid >> 4, cc = tid & 15;
        float m2v = xml[(2 * a) * 16 + cc] + xml[(2 * a + 1) * 16 + cc];
        ws[OFF_MID2 + a * D + kb + cc] = m2v;
        mi2[tid] = m2v;
    }
    __syncthreads();
    mm_core<5>(attH, mi2, ws + OFF_Z2, kb);

    gbar(bar);

    // ---- phase C: s2/P2 (redundant); out2; Y2 slice; NH; out slice ----
    if (tid < 200) {
        int pp = tid >> 2, q = tid & 3;
        int i = pp / 10, r = pp % 10;
        const float* z  = ws + OFF_Z2 + i * D;
        const float* xm = ws + OFF_XMID + r * D;
        float s = 0.f;
        for (int c = q * 192; c < q * 192 + 192; ++c) s += z[c] * xm[c];
        sred[tid] = s;
    }
    __syncthreads();
    if (tid < 50) {
        int i = tid / 10, r = tid % 10;
        float v = sred[tid * 4] + sred[tid * 4 + 1] + sred[tid * 4 + 2] + sred[tid * 4 + 3];
        s2l[tid] = ((r >> 1) == i) ? 0.f : v;
    }
    __syncthreads();
    if (tid < 5) {
        float mx = -1e30f;
#pragma unroll
        for (int r = 0; r < 10; ++r) mx = fmaxf(mx, s2l[tid * 10 + r]);
        float sm = 0.f; float e[10];
#pragma unroll
        for (int r = 0; r < 10; ++r) { e[r] = expf(s2l[tid * 10 + r] - mx); sm += e[r]; }
#pragma unroll
        for (int r = 0; r < 10; ++r) P2[tid * 10 + r] = e[r] / sm;
    }
    __syncthreads();
    for (int t = tid; t < 3840; t += 256) {
        int i = t / D, k = t - i * D;
        float v = ws[OFF_MID2 + t];
#pragma unroll
        for (int r = 0; r < 10; ++r) v += P2[i * 10 + r] * ws[OFF_XMID + r * D + k];
        out2L[t] = v;
    }
    __syncthreads();
    fullk_slice<5>(W2, out2L, red, Y2s, kb);
    if (tid < 25) {
        int a = tid / 5, b = tid % 5;
        ha[tid] = aa[(2 * a) * 10 + 2 * b] + aa[(2 * a) * 10 + 2 * b + 1]
                + aa[(2 * a + 1) * 10 + 2 * b] + aa[(2 * a + 1) * 10 + 2 * b + 1];
    }
    __syncthreads();
    if (tid < 5) {
        float s = 0.f;
#pragma unroll
        for (int j = 0; j < 5; ++j) s += (tid == j) ? 1.f : ha[tid * 5 + j];
        dh[tid] = 1.f / sqrtf(fmaxf(s, 1.f));
    }
    __syncthreads();
    if (tid < 25) {
        int i = tid / 5, j = tid % 5;
        NH[tid] = dh[i] * ((i == j) ? 1.f : ha[tid]) * dh[j];
    }
    __syncthreads();
    if (tid < 16) {
        int c = kb + tid;
        float bias = b2[c];
        float s = 0.f;
#pragma unroll
        for (int i = 0; i < 5; ++i) {
            float v = bias;
#pragma unroll
            for (int j = 0; j < 5; ++j) v += NH[i * 5 + j] * Y2s[j * 16 + tid];
            s += fmaxf(v, 0.f);
        }
        out[c] = s * 0.2f;
    }
}

// ---------------- launcher ----------------
extern "C" void kernel_launch(void* const* d_in, const int* in_sizes, int n_in,
                              void* d_out, int out_size, void* d_ws, size_t ws_size,
                              hipStream_t stream) {
    const float* x    = (const float*)d_in[0];
    const float* adj  = (const float*)d_in[1];
    const float* attL = (const float*)d_in[2];
    const float* W1   = (const float*)d_in[3];
    const float* b1   = (const float*)d_in[4];
    const float* attH = (const float*)d_in[5];
    const float* W2   = (const float*)d_in[6];
    const float* b2   = (const float*)d_in[7];
    float* ws  = (float*)d_ws;
    float* out = (float*)d_out;

    k1<<<1523, 256, 0, stream>>>(adj, x, ws);
    k2<<<1008, 256, 0, stream>>>(attL, adj, ws);
    k3<<<1088, 256, 0, stream>>>(x, adj, ws);
    k4<<<TAILB, 256, 0, stream>>>(W1, b1, attH, W2, b2, ws, out);
}